// Round 3
// baseline (2402.746 us; speedup 1.0000x reference)
//
#include <hip/hip_runtime.h>
#include <hip/hip_bf16.h>
#include <math.h>

#define T_TOK 8192
#define H_DIM 1024
#define I_DIM 2816
#define N_EXP 8
#define CAP_SLOTS 18432   // 2*T + 8*256 alignment headroom

typedef __bf16 bf16x8 __attribute__((ext_vector_type(8)));
typedef __bf16 bf16x4 __attribute__((ext_vector_type(4)));
typedef float f32x4 __attribute__((ext_vector_type(4)));

__device__ inline void gload_lds16(const void* g, void* l) {
    __builtin_amdgcn_global_load_lds((const __attribute__((address_space(1))) void*)g,
                                     (__attribute__((address_space(3))) void*)l, 16, 0, 0);
}

__device__ inline bf16x8 cvt8(float4 a, float4 b) {
    bf16x8 v;
    v[0] = (__bf16)a.x; v[1] = (__bf16)a.y; v[2] = (__bf16)a.z; v[3] = (__bf16)a.w;
    v[4] = (__bf16)b.x; v[5] = (__bf16)b.y; v[6] = (__bf16)b.z; v[7] = (__bf16)b.w;
    return v;
}

__global__ void zero_kernel(int* __restrict__ p, int n) {
    int i = blockIdx.x * 256 + threadIdx.x;
    if (i < n) p[i] = 0;
}

// f32 -> bf16, 4 elems/thread (x only)
__global__ void conv_kernel(const float* __restrict__ src, __bf16* __restrict__ dst, int n4) {
    int i = blockIdx.x * 256 + threadIdx.x;
    if (i < n4) {
        float4 v = ((const float4*)src)[i];
        bf16x4 o;
        o[0] = (__bf16)v.x; o[1] = (__bf16)v.y; o[2] = (__bf16)v.z; o[3] = (__bf16)v.w;
        ((bf16x4*)dst)[i] = o;
    }
}

// One wave per token: logits over 8 experts, softmax, top-2, renormalize.
__global__ void router_kernel(const float* __restrict__ x, const float* __restrict__ gw,
                              int* __restrict__ topi, float* __restrict__ topw,
                              int* __restrict__ counts) {
    int t = blockIdx.x * 4 + (threadIdx.x >> 6);
    int lane = threadIdx.x & 63;
    if (t >= T_TOK) return;
    const float* xr = x + (size_t)t * H_DIM;
    float s[N_EXP];
#pragma unroll
    for (int e = 0; e < N_EXP; e++) s[e] = 0.0f;
    for (int j = 0; j < H_DIM / 64; ++j) {
        float xv = xr[lane + j * 64];
#pragma unroll
        for (int e = 0; e < N_EXP; e++) s[e] += xv * gw[e * H_DIM + lane + j * 64];
    }
#pragma unroll
    for (int off = 32; off; off >>= 1) {
#pragma unroll
        for (int e = 0; e < N_EXP; e++) s[e] += __shfl_xor(s[e], off);
    }
    if (lane == 0) {
        float m = s[0];
#pragma unroll
        for (int e = 1; e < N_EXP; e++) m = fmaxf(m, s[e]);
        float p[N_EXP]; float sum = 0.0f;
#pragma unroll
        for (int e = 0; e < N_EXP; e++) { p[e] = expf(s[e] - m); sum += p[e]; }
#pragma unroll
        for (int e = 0; e < N_EXP; e++) p[e] /= sum;
        int i0 = 0;
#pragma unroll
        for (int e = 1; e < N_EXP; e++) if (p[e] > p[i0]) i0 = e;
        int i1 = (i0 == 0) ? 1 : 0;
#pragma unroll
        for (int e = 0; e < N_EXP; e++) if (e != i0 && p[e] > p[i1]) i1 = e;
        float rs = p[i0] + p[i1] + 1e-20f;
        topi[t * 2 + 0] = i0; topi[t * 2 + 1] = i1;
        topw[t * 2 + 0] = p[i0] / rs; topw[t * 2 + 1] = p[i1] / rs;
        atomicAdd(&counts[i0], 1);
        atomicAdd(&counts[i1], 1);
    }
}

__global__ void bases_kernel(const int* __restrict__ counts, int* __restrict__ bases) {
    if (threadIdx.x == 0 && blockIdx.x == 0) {
        int b = 0;
        for (int e = 0; e < N_EXP; e++) {
            bases[e] = b;
            b += ((counts[e] + 255) >> 8) << 8;   // 256-aligned regions (BM=256 tiles)
        }
    }
}

__global__ void build_kernel(const int* __restrict__ topi, const float* __restrict__ topw,
                             const int* __restrict__ bases, int* __restrict__ cursors,
                             int* __restrict__ token_ids, int* __restrict__ slot_of) {
    int t = blockIdx.x * 256 + threadIdx.x;
    if (t >= T_TOK) return;
#pragma unroll
    for (int k = 0; k < 2; k++) {
        int e = topi[t * 2 + k];
        int slot = bases[e] + atomicAdd(&cursors[e], 1);
        token_ids[slot] = t;
        slot_of[t * 2 + k] = slot;
    }
}

// Fused gate+up GEMM: 256x128 tile, BK=32, 8 waves (4x2 of 64x64).
// A (bf16) via global_load_lds width-16; B (f32 weights) reg-staged with f32->bf16 convert.
template<int K>
__global__ __launch_bounds__(512, 2)
void gateup_kernel(const __bf16* __restrict__ Xb,
                   const float* __restrict__ Wg, const float* __restrict__ Wu,
                   __bf16* __restrict__ Hid,
                   const int* __restrict__ token_ids,
                   const int* __restrict__ counts, const int* __restrict__ bases) {
    const int e = blockIdx.z;
    const int m0 = blockIdx.x * 256;
    const int n0 = blockIdx.y * 128;
    int gbase = 0;
    if (counts) {
        if (m0 >= counts[e]) return;
        gbase = bases[e];
    }
    const float* Wge = Wg + (size_t)e * I_DIM * K;
    const float* Wue = Wu + (size_t)e * I_DIM * K;

    __shared__ __bf16 As[2][256 * 32];
    __shared__ __bf16 Bgs[2][128 * 32];
    __shared__ __bf16 Bus[2][128 * 32];

    const int tid = threadIdx.x;
    const int lane = tid & 63;
    const int wid = tid >> 6;        // 0..7
    const int wm = wid >> 1, wn = wid & 1;

    // A staging (gload_lds): wave wid -> rows wid*16 + lane/4 (+128 round 2), col (lane&3)*16 B
    const int srowA = wid * 16 + (lane >> 2);
    const int colbA = (lane & 3) * 16;
    int ar0, ar1;
    if (counts) {
        ar0 = token_ids[gbase + m0 + srowA];
        ar1 = token_ids[gbase + m0 + srowA + 128];
    } else {
        ar0 = m0 + srowA; ar1 = m0 + srowA + 128;
    }
    const char* pA0 = (const char*)Xb + (size_t)ar0 * (K * 2) + colbA;
    const char* pA1 = (const char*)Xb + (size_t)ar1 * (K * 2) + colbA;
    const int ldsAoff = wid * 1024;  // bytes

    // B staging: thread -> row tid>>2 (0..127), elems (tid&3)*8
    const int srB = tid >> 2;
    const int seB = (tid & 3) * 8;
    const float* pG = Wge + (size_t)(n0 + srB) * K + seB;
    const float* pU = Wue + (size_t)(n0 + srB) * K + seB;
    const int ldsBoff = srB * 32 + seB;  // elements

    f32x4 accg[4][4], accu[4][4];
    const f32x4 z4 = {0.f, 0.f, 0.f, 0.f};
#pragma unroll
    for (int i = 0; i < 4; i++)
#pragma unroll
        for (int j = 0; j < 4; j++) { accg[i][j] = z4; accu[i][j] = z4; }

    constexpr int NT = K / 32;

    auto stage = [&](int buf, int kt) {
        const size_t koA = (size_t)kt * 64;   // bytes
        char* a_l = (char*)As[buf] + ldsAoff;
        gload_lds16(pA0 + koA, a_l);
        gload_lds16(pA1 + koA, a_l + 8192);
        const int koB = kt * 32;              // f32 elements
        float4 g0 = *(const float4*)(pG + koB);
        float4 g1 = *(const float4*)(pG + koB + 4);
        float4 u0 = *(const float4*)(pU + koB);
        float4 u1 = *(const float4*)(pU + koB + 4);
        *(bf16x8*)&Bgs[buf][ldsBoff] = cvt8(g0, g1);
        *(bf16x8*)&Bus[buf][ldsBoff] = cvt8(u0, u1);
    };

    auto compute = [&](int buf) {
        const int rA = wm * 64 + (lane & 15);
        const int rB = wn * 64 + (lane & 15);
        const int cK = (lane >> 4) * 8;
        bf16x8 a[4], g[4], u[4];
#pragma unroll
        for (int i = 0; i < 4; i++) a[i] = *(const bf16x8*)&As[buf][(rA + i * 16) * 32 + cK];
#pragma unroll
        for (int j = 0; j < 4; j++) {
            g[j] = *(const bf16x8*)&Bgs[buf][(rB + j * 16) * 32 + cK];
            u[j] = *(const bf16x8*)&Bus[buf][(rB + j * 16) * 32 + cK];
        }
#pragma unroll
        for (int i = 0; i < 4; i++)
#pragma unroll
            for (int j = 0; j < 4; j++) {
                accg[i][j] = __builtin_amdgcn_mfma_f32_16x16x32_bf16(a[i], g[j], accg[i][j], 0, 0, 0);
                accu[i][j] = __builtin_amdgcn_mfma_f32_16x16x32_bf16(a[i], u[j], accu[i][j], 0, 0, 0);
            }
    };

    stage(0, 0);
    __syncthreads();
    int cur = 0;
    for (int kt = 0; kt < NT; ++kt) {
        if (kt + 1 < NT) stage(cur ^ 1, kt + 1);
        compute(cur);
        __syncthreads();
        cur ^= 1;
    }

    const int cb = lane & 15, rb = (lane >> 4) * 4;
#pragma unroll
    for (int i = 0; i < 4; i++)
#pragma unroll
        for (int j = 0; j < 4; j++)
#pragma unroll
            for (int r = 0; r < 4; r++) {
                const int row = wm * 64 + i * 16 + rb + r;
                const int col = wn * 64 + j * 16 + cb;
                float gv = accg[i][j][r];
                float uv = accu[i][j][r];
                float h = (gv / (1.0f + __expf(-gv))) * uv;
                Hid[(size_t)(gbase + m0 + row) * I_DIM + n0 + col] = (__bf16)h;
            }
}

// Down-proj GEMM: 256x128 tile, A (hidden bf16) via gload_lds, B (f32) reg-staged.
template<int K>
__global__ __launch_bounds__(512, 2)
void down_kernel(const __bf16* __restrict__ Hin, const float* __restrict__ Wd,
                 __bf16* __restrict__ Oout,
                 const int* __restrict__ counts, const int* __restrict__ bases) {
    const int e = blockIdx.z;
    const int m0 = blockIdx.x * 256;
    const int n0 = blockIdx.y * 128;
    int gbase = 0;
    if (counts) {
        if (m0 >= counts[e]) return;
        gbase = bases[e];
    }
    const float* Wde = Wd + (size_t)e * H_DIM * K;

    __shared__ __bf16 As[2][256 * 32];
    __shared__ __bf16 Bs[2][128 * 32];

    const int tid = threadIdx.x;
    const int lane = tid & 63;
    const int wid = tid >> 6;
    const int wm = wid >> 1, wn = wid & 1;

    const int srowA = wid * 16 + (lane >> 2);
    const int colbA = (lane & 3) * 16;
    const char* pA0 = (const char*)Hin + (size_t)(gbase + m0 + srowA) * (K * 2) + colbA;
    const char* pA1 = (const char*)Hin + (size_t)(gbase + m0 + srowA + 128) * (K * 2) + colbA;
    const int ldsAoff = wid * 1024;

    const int srB = tid >> 2;
    const int seB = (tid & 3) * 8;
    const float* pB = Wde + (size_t)(n0 + srB) * K + seB;
    const int ldsBoff = srB * 32 + seB;

    f32x4 acc[4][4];
    const f32x4 z4 = {0.f, 0.f, 0.f, 0.f};
#pragma unroll
    for (int i = 0; i < 4; i++)
#pragma unroll
        for (int j = 0; j < 4; j++) acc[i][j] = z4;

    constexpr int NT = K / 32;

    auto stage = [&](int buf, int kt) {
        const size_t koA = (size_t)kt * 64;
        char* a_l = (char*)As[buf] + ldsAoff;
        gload_lds16(pA0 + koA, a_l);
        gload_lds16(pA1 + koA, a_l + 8192);
        const int koB = kt * 32;
        float4 b0 = *(const float4*)(pB + koB);
        float4 b1 = *(const float4*)(pB + koB + 4);
        *(bf16x8*)&Bs[buf][ldsBoff] = cvt8(b0, b1);
    };

    auto compute = [&](int buf) {
        const int rA = wm * 64 + (lane & 15);
        const int rB = wn * 64 + (lane & 15);
        const int cK = (lane >> 4) * 8;
        bf16x8 a[4], b[4];
#pragma unroll
        for (int i = 0; i < 4; i++) a[i] = *(const bf16x8*)&As[buf][(rA + i * 16) * 32 + cK];
#pragma unroll
        for (int j = 0; j < 4; j++) b[j] = *(const bf16x8*)&Bs[buf][(rB + j * 16) * 32 + cK];
#pragma unroll
        for (int i = 0; i < 4; i++)
#pragma unroll
            for (int j = 0; j < 4; j++)
                acc[i][j] = __builtin_amdgcn_mfma_f32_16x16x32_bf16(a[i], b[j], acc[i][j], 0, 0, 0);
    };

    stage(0, 0);
    __syncthreads();
    int cur = 0;
    for (int kt = 0; kt < NT; ++kt) {
        if (kt + 1 < NT) stage(cur ^ 1, kt + 1);
        compute(cur);
        __syncthreads();
        cur ^= 1;
    }

    const int cb = lane & 15, rb = (lane >> 4) * 4;
#pragma unroll
    for (int i = 0; i < 4; i++)
#pragma unroll
        for (int j = 0; j < 4; j++)
#pragma unroll
            for (int r = 0; r < 4; r++) {
                const int row = wm * 64 + i * 16 + rb + r;
                const int col = wn * 64 + j * 16 + cb;
                Oout[(size_t)(gbase + m0 + row) * H_DIM + n0 + col] = (__bf16)acc[i][j][r];
            }
}

// out[t][h] = sh[t][h] + w0*rt[slot0][h] + w1*rt[slot1][h]
__global__ void combine_kernel(const __bf16* __restrict__ sh, const __bf16* __restrict__ rt,
                               const int* __restrict__ slot_of, const float* __restrict__ topw,
                               float* __restrict__ out) {
    int gid = blockIdx.x * 256 + threadIdx.x;
    int t = gid >> 8;
    int h = (gid & 255) * 4;
    int s0 = slot_of[t * 2], s1 = slot_of[t * 2 + 1];
    float w0 = topw[t * 2], w1 = topw[t * 2 + 1];
    bf16x4 a = *(const bf16x4*)&sh[(size_t)t * H_DIM + h];
    bf16x4 b = *(const bf16x4*)&rt[(size_t)s0 * H_DIM + h];
    bf16x4 c = *(const bf16x4*)&rt[(size_t)s1 * H_DIM + h];
    float4 o;
    o.x = (float)a[0] + w0 * (float)b[0] + w1 * (float)c[0];
    o.y = (float)a[1] + w0 * (float)b[1] + w1 * (float)c[1];
    o.z = (float)a[2] + w0 * (float)b[2] + w1 * (float)c[2];
    o.w = (float)a[3] + w0 * (float)b[3] + w1 * (float)c[3];
    *(float4*)&out[(size_t)t * H_DIM + h] = o;
}

extern "C" void kernel_launch(void* const* d_in, const int* in_sizes, int n_in,
                              void* d_out, int out_size, void* d_ws, size_t ws_size,
                              hipStream_t stream) {
    const float* x = (const float*)d_in[0];
    const float* gate_w = (const float*)d_in[1];
    const float* expert_gate = (const float*)d_in[2];
    const float* expert_up = (const float*)d_in[3];
    const float* expert_down = (const float*)d_in[4];
    const float* shared_gate = (const float*)d_in[5];
    const float* shared_up = (const float*)d_in[6];
    const float* shared_down = (const float*)d_in[7];
    float* out = (float*)d_out;

    char* w = (char*)d_ws;
    size_t off = 0;
    auto alloc = [&](size_t bytes) {
        void* p = w + off;
        off = (off + bytes + 255) & ~(size_t)255;
        return p;
    };

    // Workspace budget ~184 MB (R0's passing layout proved >=162 MB available).
    __bf16* xb = (__bf16*)alloc((size_t)T_TOK * H_DIM * 2);            // 16.8 MB
    __bf16* hid_sh = (__bf16*)alloc((size_t)T_TOK * I_DIM * 2);        // 46.1 MB
    __bf16* hid_rt = (__bf16*)alloc((size_t)CAP_SLOTS * I_DIM * 2);    // 103.8 MB
    __bf16* sh_out = (__bf16*)alloc((size_t)T_TOK * H_DIM * 2);        // 16.8 MB
    __bf16* r_out = hid_sh;  // alias: hid_sh dead after shared down (37.8 <= 46.1 MB)
    int* topi = (int*)alloc((size_t)T_TOK * 2 * 4);
    float* topw = (float*)alloc((size_t)T_TOK * 2 * 4);
    int* slot_of = (int*)alloc((size_t)T_TOK * 2 * 4);
    // misc (zeroed): counts[8] | cursors[8] | bases[8] | pad | token_ids[CAP]
    const size_t misc_bytes = 128 + (size_t)CAP_SLOTS * 4;
    char* misc = (char*)alloc(misc_bytes);
    int* counts = (int*)misc;
    int* cursors = counts + 8;
    int* bases = cursors + 8;
    int* token_ids = (int*)(misc + 128);

    // 1) zero router state + token_ids (padding slots -> token 0)
    int zero_n = (int)(misc_bytes / 4);
    zero_kernel<<<(zero_n + 255) / 256, 256, 0, stream>>>((int*)misc, zero_n);

    // 2) x -> bf16
    {
        int n4 = T_TOK * H_DIM / 4;
        conv_kernel<<<(n4 + 255) / 256, 256, 0, stream>>>(x, xb, n4);
    }

    // 3) router -> bases -> gather lists
    router_kernel<<<T_TOK / 4, 256, 0, stream>>>(x, gate_w, topi, topw, counts);
    bases_kernel<<<1, 64, 0, stream>>>(counts, bases);
    build_kernel<<<T_TOK / 256, 256, 0, stream>>>(topi, topw, bases, cursors, token_ids, slot_of);

    // 4) shared expert
    gateup_kernel<H_DIM><<<dim3(T_TOK / 256, I_DIM / 128, 1), 512, 0, stream>>>(
        xb, shared_gate, shared_up, hid_sh, nullptr, nullptr, nullptr);
    down_kernel<I_DIM><<<dim3(T_TOK / 256, H_DIM / 128, 1), 512, 0, stream>>>(
        hid_sh, shared_down, sh_out, nullptr, nullptr);

    // 5) routed experts (gathered rows, per-expert z); r_out aliases hid_sh (now dead)
    gateup_kernel<H_DIM><<<dim3(T_TOK / 256, I_DIM / 128, N_EXP), 512, 0, stream>>>(
        xb, expert_gate, expert_up, hid_rt, token_ids, counts, bases);
    down_kernel<I_DIM><<<dim3(T_TOK / 256, H_DIM / 128, N_EXP), 512, 0, stream>>>(
        hid_rt, expert_down, r_out, counts, bases);

    // 6) combine: out = shared + w0*routed0 + w1*routed1
    combine_kernel<<<T_TOK, 256, 0, stream>>>(sh_out, r_out, slot_of, topw, out);
}

// Round 5
// 1199.398 us; speedup vs baseline: 2.0033x; 2.0033x over previous
//
#include <hip/hip_runtime.h>
#include <hip/hip_bf16.h>
#include <math.h>

#define T_TOK 8192
#define H_DIM 1024
#define I_DIM 2816
#define N_EXP 8
#define NREG  16           // (expert, k) regions
#define CAP_SLOTS 18432    // 2*T + 16*128 alignment headroom
#define MAX_TILES 144      // CAP_SLOTS / 128

typedef __bf16 bf16x8 __attribute__((ext_vector_type(8)));
typedef __bf16 bf16x4 __attribute__((ext_vector_type(4)));
typedef float f32x4 __attribute__((ext_vector_type(4)));

__device__ inline void gload_lds16(const void* g, void* l) {
    __builtin_amdgcn_global_load_lds((const __attribute__((address_space(1))) void*)g,
                                     (__attribute__((address_space(3))) void*)l, 16, 0, 0);
}

__global__ void zero_kernel(int* __restrict__ p, int n) {
    int i = blockIdx.x * 256 + threadIdx.x;
    if (i < n) p[i] = 0;
}

__global__ void fillm1_kernel(int* __restrict__ p, int n) {
    int i = blockIdx.x * 256 + threadIdx.x;
    if (i < n) p[i] = -1;
}

// f32 -> bf16, 4 elems/thread
__global__ void conv_kernel(const float* __restrict__ src, __bf16* __restrict__ dst, int n4) {
    int i = blockIdx.x * 256 + threadIdx.x;
    if (i < n4) {
        float4 v = ((const float4*)src)[i];
        bf16x4 o;
        o[0] = (__bf16)v.x; o[1] = (__bf16)v.y; o[2] = (__bf16)v.z; o[3] = (__bf16)v.w;
        ((bf16x4*)dst)[i] = o;
    }
}

// One wave per token: logits over 8 experts, softmax, top-2, renormalize.
// counts2 indexed by region r = e*2 + k.
__global__ void router_kernel(const float* __restrict__ x, const float* __restrict__ gw,
                              int* __restrict__ topi, float* __restrict__ topw,
                              int* __restrict__ counts2) {
    int t = blockIdx.x * 4 + (threadIdx.x >> 6);
    int lane = threadIdx.x & 63;
    if (t >= T_TOK) return;
    const float* xr = x + (size_t)t * H_DIM;
    float s[N_EXP];
#pragma unroll
    for (int e = 0; e < N_EXP; e++) s[e] = 0.0f;
    for (int j = 0; j < H_DIM / 64; ++j) {
        float xv = xr[lane + j * 64];
#pragma unroll
        for (int e = 0; e < N_EXP; e++) s[e] += xv * gw[e * H_DIM + lane + j * 64];
    }
#pragma unroll
    for (int off = 32; off; off >>= 1) {
#pragma unroll
        for (int e = 0; e < N_EXP; e++) s[e] += __shfl_xor(s[e], off);
    }
    if (lane == 0) {
        float m = s[0];
#pragma unroll
        for (int e = 1; e < N_EXP; e++) m = fmaxf(m, s[e]);
        float p[N_EXP]; float sum = 0.0f;
#pragma unroll
        for (int e = 0; e < N_EXP; e++) { p[e] = expf(s[e] - m); sum += p[e]; }
#pragma unroll
        for (int e = 0; e < N_EXP; e++) p[e] /= sum;
        int i0 = 0;
#pragma unroll
        for (int e = 1; e < N_EXP; e++) if (p[e] > p[i0]) i0 = e;
        int i1 = (i0 == 0) ? 1 : 0;
#pragma unroll
        for (int e = 0; e < N_EXP; e++) if (e != i0 && p[e] > p[i1]) i1 = e;
        float rs = p[i0] + p[i1] + 1e-20f;
        topi[t * 2 + 0] = i0; topi[t * 2 + 1] = i1;
        topw[t * 2 + 0] = p[i0] / rs; topw[t * 2 + 1] = p[i1] / rs;
        atomicAdd(&counts2[i0 * 2 + 0], 1);
        atomicAdd(&counts2[i1 * 2 + 1], 1);
    }
}

// Single thread: 128-aligned region bases + tile -> (expert, k) tables.
__global__ void bases_tiles_kernel(const int* __restrict__ counts2, int* __restrict__ bases2,
                                   int* __restrict__ tile_e, int* __restrict__ tile_k) {
    if (threadIdx.x != 0 || blockIdx.x != 0) return;
    int b = 0;
    int t = 0;
    for (int r = 0; r < NREG; r++) {
        bases2[r] = b;
        int nt = (counts2[r] + 127) >> 7;
        for (int i = 0; i < nt; i++) { tile_e[t] = r >> 1; tile_k[t] = r & 1; t++; }
        b += nt << 7;
    }
    for (; t < MAX_TILES; t++) { tile_e[t] = -1; tile_k[t] = -1; }
}

__global__ void build_kernel(const int* __restrict__ topi, const float* __restrict__ topw,
                             const int* __restrict__ bases2, int* __restrict__ cursors2,
                             int* __restrict__ token_ids, float* __restrict__ token_w) {
    int t = blockIdx.x * 256 + threadIdx.x;
    if (t >= T_TOK) return;
#pragma unroll
    for (int k = 0; k < 2; k++) {
        int r = topi[t * 2 + k] * 2 + k;
        int slot = bases2[r] + atomicAdd(&cursors2[r], 1);
        token_ids[slot] = t;
        token_w[slot] = topw[t * 2 + k];
    }
}

// m97-shape GEMM: 128x128 tile, BK=32, 4 waves (2x2 of 64x64), linear LDS 32KB,
// both operands bf16 via global_load_lds width-16, double-buffered.
// EPI: 0=gate(silu->hid) 1=up(hid*=v) 2=down_shared(out=v) 3=down_routed(out[tok]+=w*v)
template<int EPI, int KDIM, int NBROWS>
__global__ __launch_bounds__(256, 4)
void gemm_k(const __bf16* __restrict__ A, const __bf16* __restrict__ B,
            __bf16* __restrict__ hid, float* __restrict__ out,
            const int* __restrict__ token_ids, const float* __restrict__ token_w,
            const int* __restrict__ tile_e, const int* __restrict__ tile_k, int ksel) {
    const int bx = blockIdx.x, by = blockIdx.y;
    int e = 0;
    if (tile_e) {
        e = tile_e[bx];
        if (e < 0) return;
        if (EPI == 3 && tile_k[bx] != ksel) return;
    }
    const int m0 = bx * 128, n0 = by * 128;

    __shared__ __bf16 As[2][128 * 32];
    __shared__ __bf16 Bs[2][128 * 32];

    const int tid = threadIdx.x, lane = tid & 63, wid = tid >> 6;
    const int wm = wid >> 1, wn = wid & 1;

    // staging map: wave wid -> rows wid*16 + lane/4 (and +64), byte col (lane&3)*16
    const int srow = wid * 16 + (lane >> 2);
    const int colb = (lane & 3) * 16;

    int ar0, ar1;
    if (EPI <= 1 && token_ids) {  // routed gate/up: gather token rows
        int t0 = token_ids[m0 + srow], t1 = token_ids[m0 + srow + 64];
        ar0 = t0 < 0 ? 0 : t0;
        ar1 = t1 < 0 ? 0 : t1;
    } else {
        ar0 = m0 + srow; ar1 = m0 + srow + 64;
    }
    const char* pA0 = (const char*)A + (size_t)ar0 * (KDIM * 2) + colb;
    const char* pA1 = (const char*)A + (size_t)ar1 * (KDIM * 2) + colb;
    const char* pB0 = (const char*)B + ((size_t)e * NBROWS + n0 + srow) * (KDIM * 2) + colb;
    const char* pB1 = pB0 + (size_t)64 * (KDIM * 2);
    const int ldsoff = wid * 1024;  // bytes

    f32x4 acc[4][4];
    const f32x4 z4 = {0.f, 0.f, 0.f, 0.f};
#pragma unroll
    for (int i = 0; i < 4; i++)
#pragma unroll
        for (int j = 0; j < 4; j++) acc[i][j] = z4;

    constexpr int NT = KDIM / 32;

    auto stage = [&](int buf, int kt) {
        const size_t ko = (size_t)kt * 64;  // BK=32 bf16 = 64B
        char* a_l = (char*)As[buf] + ldsoff;
        gload_lds16(pA0 + ko, a_l);
        gload_lds16(pA1 + ko, a_l + 4096);
        char* b_l = (char*)Bs[buf] + ldsoff;
        gload_lds16(pB0 + ko, b_l);
        gload_lds16(pB1 + ko, b_l + 4096);
    };

    auto compute = [&](int buf) {
        const int rA = wm * 64 + (lane & 15);
        const int rB = wn * 64 + (lane & 15);
        const int cK = (lane >> 4) * 8;
        bf16x8 a[4], b[4];
#pragma unroll
        for (int i = 0; i < 4; i++) a[i] = *(const bf16x8*)&As[buf][(rA + i * 16) * 32 + cK];
#pragma unroll
        for (int j = 0; j < 4; j++) b[j] = *(const bf16x8*)&Bs[buf][(rB + j * 16) * 32 + cK];
#pragma unroll
        for (int i = 0; i < 4; i++)
#pragma unroll
            for (int j = 0; j < 4; j++)
                acc[i][j] = __builtin_amdgcn_mfma_f32_16x16x32_bf16(a[i], b[j], acc[i][j], 0, 0, 0);
    };

    stage(0, 0);
    __syncthreads();
    int cur = 0;
    for (int kt = 0; kt < NT; ++kt) {
        if (kt + 1 < NT) stage(cur ^ 1, kt + 1);
        compute(cur);
        __syncthreads();
        cur ^= 1;
    }

    // C/D layout: col = lane&15, row = (lane>>4)*4 + reg  [m89/m91]
    const int cb = lane & 15, rb = (lane >> 4) * 4;
#pragma unroll
    for (int i = 0; i < 4; i++)
#pragma unroll
        for (int j = 0; j < 4; j++)
#pragma unroll
            for (int r = 0; r < 4; r++) {
                const int row = wm * 64 + i * 16 + rb + r;
                const int col = n0 + wn * 64 + j * 16 + cb;
                float v = acc[i][j][r];
                if (EPI == 0) {
                    float sv = v / (1.0f + __expf(-v));
                    hid[(size_t)(m0 + row) * NBROWS + col] = (__bf16)sv;
                } else if (EPI == 1) {
                    size_t idx = (size_t)(m0 + row) * NBROWS + col;
                    hid[idx] = (__bf16)((float)hid[idx] * v);
                } else if (EPI == 2) {
                    out[(size_t)(m0 + row) * H_DIM + col] = v;
                } else {
                    int slot = m0 + row;
                    int tok = token_ids[slot];
                    if (tok >= 0) {
                        size_t o = (size_t)tok * H_DIM + col;
                        out[o] += token_w[slot] * v;   // k-split: no same-token race
                    }
                }
            }
}

extern "C" void kernel_launch(void* const* d_in, const int* in_sizes, int n_in,
                              void* d_out, int out_size, void* d_ws, size_t ws_size,
                              hipStream_t stream) {
    const float* x = (const float*)d_in[0];
    const float* gate_w = (const float*)d_in[1];
    const float* expert_gate = (const float*)d_in[2];
    const float* expert_up = (const float*)d_in[3];
    const float* expert_down = (const float*)d_in[4];
    const float* shared_gate = (const float*)d_in[5];
    const float* shared_up = (const float*)d_in[6];
    const float* shared_down = (const float*)d_in[7];
    float* out = (float*)d_out;

    char* w = (char*)d_ws;
    size_t off = 0;
    auto alloc = [&](size_t bytes) {
        void* p = w + off;
        off = (off + bytes + 255) & ~(size_t)255;
        return p;
    };

    // Peak ~167 MB (R2 proved >= 184 MB available).
    __bf16* xb = (__bf16*)alloc((size_t)T_TOK * H_DIM * 2);                 // 16.8 MB
    __bf16* wbuf = (__bf16*)alloc((size_t)N_EXP * I_DIM * H_DIM * 2);       // 46.1 MB (reused 6x)
    __bf16* hid = (__bf16*)alloc((size_t)CAP_SLOTS * I_DIM * 2);            // 103.8 MB
    int* topi = (int*)alloc((size_t)T_TOK * 2 * 4);
    float* topw = (float*)alloc((size_t)T_TOK * 2 * 4);
    // counts2 and cursors2 MUST be one contiguous block (zeroed together).
    int* ctrs = (int*)alloc(2 * NREG * 4);
    int* counts2 = ctrs;
    int* cursors2 = ctrs + NREG;
    int* bases2 = (int*)alloc(NREG * 4);
    int* tile_e = (int*)alloc(MAX_TILES * 4);
    int* tile_k = (int*)alloc(MAX_TILES * 4);
    int* token_ids = (int*)alloc((size_t)CAP_SLOTS * 4);
    float* token_w = (float*)alloc((size_t)CAP_SLOTS * 4);

    // 1) init routing state (counts2+cursors2 contiguous -> one zero pass)
    zero_kernel<<<1, 256, 0, stream>>>(ctrs, 2 * NREG);
    fillm1_kernel<<<CAP_SLOTS / 256, 256, 0, stream>>>(token_ids, CAP_SLOTS);

    // 2) x -> bf16
    conv_kernel<<<T_TOK * H_DIM / 1024, 256, 0, stream>>>(x, xb, T_TOK * H_DIM / 4);

    // 3) router -> bases/tiles -> gather lists
    router_kernel<<<T_TOK / 4, 256, 0, stream>>>(x, gate_w, topi, topw, counts2);
    bases_tiles_kernel<<<1, 64, 0, stream>>>(counts2, bases2, tile_e, tile_k);
    build_kernel<<<T_TOK / 256, 256, 0, stream>>>(topi, topw, bases2, cursors2, token_ids, token_w);

    const int nI4 = I_DIM * H_DIM / 4;            // one shared proj, f32x4 count
    const int nE4 = N_EXP * I_DIM * H_DIM / 4;    // all-expert proj

    // 4) shared expert: gate -> up(RMW) -> down(writes out directly)
    conv_kernel<<<nI4 / 256, 256, 0, stream>>>(shared_gate, wbuf, nI4);
    gemm_k<0, H_DIM, I_DIM><<<dim3(T_TOK / 128, I_DIM / 128), 256, 0, stream>>>(
        xb, wbuf, hid, nullptr, nullptr, nullptr, nullptr, nullptr, 0);
    conv_kernel<<<nI4 / 256, 256, 0, stream>>>(shared_up, wbuf, nI4);
    gemm_k<1, H_DIM, I_DIM><<<dim3(T_TOK / 128, I_DIM / 128), 256, 0, stream>>>(
        xb, wbuf, hid, nullptr, nullptr, nullptr, nullptr, nullptr, 0);
    conv_kernel<<<nI4 / 256, 256, 0, stream>>>(shared_down, wbuf, nI4);
    gemm_k<2, I_DIM, H_DIM><<<dim3(T_TOK / 128, H_DIM / 128), 256, 0, stream>>>(
        hid, wbuf, nullptr, out, nullptr, nullptr, nullptr, nullptr, 0);

    // 5) routed experts: gate -> up(RMW) -> down k0/k1 (RMW out, no races)
    conv_kernel<<<nE4 / 256, 256, 0, stream>>>(expert_gate, wbuf, nE4);
    gemm_k<0, H_DIM, I_DIM><<<dim3(MAX_TILES, I_DIM / 128), 256, 0, stream>>>(
        xb, wbuf, hid, nullptr, token_ids, token_w, tile_e, tile_k, 0);
    conv_kernel<<<nE4 / 256, 256, 0, stream>>>(expert_up, wbuf, nE4);
    gemm_k<1, H_DIM, I_DIM><<<dim3(MAX_TILES, I_DIM / 128), 256, 0, stream>>>(
        xb, wbuf, hid, nullptr, token_ids, token_w, tile_e, tile_k, 0);
    conv_kernel<<<nE4 / 256, 256, 0, stream>>>(expert_down, wbuf, nE4);
    gemm_k<3, I_DIM, H_DIM><<<dim3(MAX_TILES, H_DIM / 128), 256, 0, stream>>>(
        hid, wbuf, nullptr, out, token_ids, token_w, tile_e, tile_k, 0);
    gemm_k<3, I_DIM, H_DIM><<<dim3(MAX_TILES, H_DIM / 128), 256, 0, stream>>>(
        hid, wbuf, nullptr, out, token_ids, token_w, tile_e, tile_k, 1);
}

// Round 6
// 1002.425 us; speedup vs baseline: 2.3969x; 1.1965x over previous
//
#include <hip/hip_runtime.h>
#include <hip/hip_bf16.h>
#include <math.h>

#define T_TOK 8192
#define H_DIM 1024
#define I_DIM 2816
#define N_EXP 8
#define NREG  16           // (expert, k) regions
#define CAP_SLOTS 18432    // 2*T + 16*128 alignment headroom
#define MAX_TILES 144      // CAP_SLOTS / 128

typedef __bf16 bf16x8 __attribute__((ext_vector_type(8)));
typedef __bf16 bf16x4 __attribute__((ext_vector_type(4)));
typedef float f32x4 __attribute__((ext_vector_type(4)));

__device__ inline void gload_lds16(const void* g, void* l) {
    __builtin_amdgcn_global_load_lds((const __attribute__((address_space(1))) void*)g,
                                     (__attribute__((address_space(3))) void*)l, 16, 0, 0);
}

// f32 -> bf16, 4 elems/thread
__global__ void conv_kernel(const float* __restrict__ src, __bf16* __restrict__ dst, int n4) {
    int i = blockIdx.x * 256 + threadIdx.x;
    if (i < n4) {
        float4 v = ((const float4*)src)[i];
        bf16x4 o;
        o[0] = (__bf16)v.x; o[1] = (__bf16)v.y; o[2] = (__bf16)v.z; o[3] = (__bf16)v.w;
        ((bf16x4*)dst)[i] = o;
    }
}

// One wave per token: logits over 8 experts (float4-vectorized), softmax, top-2,
// renormalize. NO atomics (they cost 190us of cacheline ping-pong in R4).
__global__ void router_kernel(const float* __restrict__ x, const float* __restrict__ gw,
                              int* __restrict__ topi, float* __restrict__ topw) {
    int t = blockIdx.x * 4 + (threadIdx.x >> 6);
    int lane = threadIdx.x & 63;
    if (t >= T_TOK) return;
    const float4* xr = (const float4*)(x + (size_t)t * H_DIM);
    float s[N_EXP];
#pragma unroll
    for (int e = 0; e < N_EXP; e++) s[e] = 0.0f;
#pragma unroll
    for (int j = 0; j < H_DIM / 256; ++j) {
        float4 xv = xr[j * 64 + lane];
#pragma unroll
        for (int e = 0; e < N_EXP; e++) {
            float4 gv = ((const float4*)(gw + (size_t)e * H_DIM))[j * 64 + lane];
            s[e] += xv.x * gv.x + xv.y * gv.y + xv.z * gv.z + xv.w * gv.w;
        }
    }
#pragma unroll
    for (int off = 32; off; off >>= 1) {
#pragma unroll
        for (int e = 0; e < N_EXP; e++) s[e] += __shfl_xor(s[e], off);
    }
    if (lane == 0) {
        float m = s[0];
#pragma unroll
        for (int e = 1; e < N_EXP; e++) m = fmaxf(m, s[e]);
        float p[N_EXP]; float sum = 0.0f;
#pragma unroll
        for (int e = 0; e < N_EXP; e++) { p[e] = expf(s[e] - m); sum += p[e]; }
#pragma unroll
        for (int e = 0; e < N_EXP; e++) p[e] /= sum;
        int i0 = 0;
#pragma unroll
        for (int e = 1; e < N_EXP; e++) if (p[e] > p[i0]) i0 = e;
        int i1 = (i0 == 0) ? 1 : 0;
#pragma unroll
        for (int e = 0; e < N_EXP; e++) if (e != i0 && p[e] > p[i1]) i1 = e;
        float rs = p[i0] + p[i1] + 1e-20f;
        topi[t * 2 + 0] = i0; topi[t * 2 + 1] = i1;
        topw[t * 2 + 0] = p[i0] / rs; topw[t * 2 + 1] = p[i1] / rs;
    }
}

// Single-wave routing build: histogram -> bases -> tile tables -> slot assignment.
// Replaces zero/fillm1/bases_tiles/build kernels; zero global atomics.
#define NE_PER (T_TOK * 2 / 64)   // entries per lane = 512... (16384/64 = 256)
__global__ void route_build_kernel(const int* __restrict__ topi, const float* __restrict__ topw,
                                   int* __restrict__ token_ids, float* __restrict__ token_w,
                                   int* __restrict__ tile_e, int* __restrict__ tile_k) {
    __shared__ int h[64][NREG];
    __shared__ int bases[NREG];
    __shared__ int cur[64][NREG];
    const int lane = threadIdx.x;   // 0..63, single wave

    // 1) fill all slots with token -1 (padding)
    for (int i = lane; i < CAP_SLOTS; i += 64) token_ids[i] = -1;

    // 2) per-lane histogram over lane-strided entries (coalesced topi reads)
#pragma unroll
    for (int r = 0; r < NREG; r++) h[lane][r] = 0;
    for (int i = 0; i < T_TOK * 2 / 64; i++) {
        int entry = i * 64 + lane;
        int r = topi[entry] * 2 + (entry & 1);
        h[lane][r]++;
    }
    __syncthreads();

    // 3) region counts
    if (lane < NREG) {
        int c = 0;
        for (int l = 0; l < 64; l++) c += h[l][lane];
        bases[lane] = c;   // raw count, converted to base below
    }
    __syncthreads();

    // 4) 128-aligned bases + tile -> (expert,k) tables (serial, tiny)
    if (lane == 0) {
        int b = 0, t = 0;
        for (int r = 0; r < NREG; r++) {
            int c = bases[r];
            int nt = (c + 127) >> 7;
            bases[r] = b;
            for (int i = 0; i < nt; i++) { tile_e[t] = r >> 1; tile_k[t] = r & 1; t++; }
            b += nt << 7;
        }
        for (; t < MAX_TILES; t++) { tile_e[t] = -1; tile_k[t] = -1; }
    }
    __syncthreads();

    // 5) per-lane cursors: bases[r] + sum_{l<lane} h[l][r]
    for (int r = 0; r < NREG; r++) {
        int s = bases[r];
        for (int l = 0; l < lane; l++) s += h[l][r];
        cur[lane][r] = s;
    }
    __syncthreads();

    // 6) assign slots (same lane-strided walk => matches histogram)
    for (int i = 0; i < T_TOK * 2 / 64; i++) {
        int entry = i * 64 + lane;
        int r = topi[entry] * 2 + (entry & 1);
        int slot = cur[lane][r]++;
        token_ids[slot] = entry >> 1;
        token_w[slot] = topw[entry];
    }
}

// m97-shape GEMM: 128x128 tile, BK=32, 4 waves (2x2 of 64x64), linear LDS 32KB,
// both operands bf16 via global_load_lds width-16, double-buffered.
// EPI: 0=gate(silu->hid) 1=up(hid*=v) 2=down_shared(out=v) 3=down_routed(out[tok]+=w*v)
template<int EPI, int KDIM, int NBROWS>
__global__ __launch_bounds__(256, 4)
void gemm_k(const __bf16* __restrict__ A, const __bf16* __restrict__ B,
            __bf16* __restrict__ hid, float* __restrict__ out,
            const int* __restrict__ token_ids, const float* __restrict__ token_w,
            const int* __restrict__ tile_e, const int* __restrict__ tile_k, int ksel) {
    const int bx = blockIdx.x, by = blockIdx.y;
    int e = 0;
    if (tile_e) {
        e = tile_e[bx];
        if (e < 0) return;
        if (EPI == 3 && tile_k[bx] != ksel) return;
    }
    const int m0 = bx * 128, n0 = by * 128;

    __shared__ __bf16 As[2][128 * 32];
    __shared__ __bf16 Bs[2][128 * 32];

    const int tid = threadIdx.x, lane = tid & 63, wid = tid >> 6;
    const int wm = wid >> 1, wn = wid & 1;

    // staging map: wave wid -> rows wid*16 + lane/4 (and +64), byte col (lane&3)*16
    const int srow = wid * 16 + (lane >> 2);
    const int colb = (lane & 3) * 16;

    int ar0, ar1;
    if (EPI <= 1 && token_ids) {  // routed gate/up: gather token rows
        int t0 = token_ids[m0 + srow], t1 = token_ids[m0 + srow + 64];
        ar0 = t0 < 0 ? 0 : t0;
        ar1 = t1 < 0 ? 0 : t1;
    } else {
        ar0 = m0 + srow; ar1 = m0 + srow + 64;
    }
    const char* pA0 = (const char*)A + (size_t)ar0 * (KDIM * 2) + colb;
    const char* pA1 = (const char*)A + (size_t)ar1 * (KDIM * 2) + colb;
    const char* pB0 = (const char*)B + ((size_t)e * NBROWS + n0 + srow) * (KDIM * 2) + colb;
    const char* pB1 = pB0 + (size_t)64 * (KDIM * 2);
    const int ldsoff = wid * 1024;  // bytes

    f32x4 acc[4][4];
    const f32x4 z4 = {0.f, 0.f, 0.f, 0.f};
#pragma unroll
    for (int i = 0; i < 4; i++)
#pragma unroll
        for (int j = 0; j < 4; j++) acc[i][j] = z4;

    constexpr int NT = KDIM / 32;

    auto stage = [&](int buf, int kt) {
        const size_t ko = (size_t)kt * 64;  // BK=32 bf16 = 64B
        char* a_l = (char*)As[buf] + ldsoff;
        gload_lds16(pA0 + ko, a_l);
        gload_lds16(pA1 + ko, a_l + 4096);
        char* b_l = (char*)Bs[buf] + ldsoff;
        gload_lds16(pB0 + ko, b_l);
        gload_lds16(pB1 + ko, b_l + 4096);
    };

    auto compute = [&](int buf) {
        const int rA = wm * 64 + (lane & 15);
        const int rB = wn * 64 + (lane & 15);
        const int cK = (lane >> 4) * 8;
        bf16x8 a[4], b[4];
#pragma unroll
        for (int i = 0; i < 4; i++) a[i] = *(const bf16x8*)&As[buf][(rA + i * 16) * 32 + cK];
#pragma unroll
        for (int j = 0; j < 4; j++) b[j] = *(const bf16x8*)&Bs[buf][(rB + j * 16) * 32 + cK];
#pragma unroll
        for (int i = 0; i < 4; i++)
#pragma unroll
            for (int j = 0; j < 4; j++)
                acc[i][j] = __builtin_amdgcn_mfma_f32_16x16x32_bf16(a[i], b[j], acc[i][j], 0, 0, 0);
    };

    stage(0, 0);
    __syncthreads();
    int cur = 0;
    for (int kt = 0; kt < NT; ++kt) {
        if (kt + 1 < NT) stage(cur ^ 1, kt + 1);
        compute(cur);
        __syncthreads();
        cur ^= 1;
    }

    // C/D layout: col = lane&15, row = (lane>>4)*4 + reg  [m89/m91]
    const int cb = lane & 15, rb = (lane >> 4) * 4;
#pragma unroll
    for (int i = 0; i < 4; i++)
#pragma unroll
        for (int j = 0; j < 4; j++)
#pragma unroll
            for (int r = 0; r < 4; r++) {
                const int row = wm * 64 + i * 16 + rb + r;
                const int col = n0 + wn * 64 + j * 16 + cb;
                float v = acc[i][j][r];
                if (EPI == 0) {
                    float sv = v / (1.0f + __expf(-v));
                    hid[(size_t)(m0 + row) * NBROWS + col] = (__bf16)sv;
                } else if (EPI == 1) {
                    size_t idx = (size_t)(m0 + row) * NBROWS + col;
                    hid[idx] = (__bf16)((float)hid[idx] * v);
                } else if (EPI == 2) {
                    out[(size_t)(m0 + row) * H_DIM + col] = v;
                } else {
                    int slot = m0 + row;
                    int tok = token_ids[slot];
                    if (tok >= 0) {
                        size_t o = (size_t)tok * H_DIM + col;
                        out[o] += token_w[slot] * v;   // k-split: no same-token race
                    }
                }
            }
}

extern "C" void kernel_launch(void* const* d_in, const int* in_sizes, int n_in,
                              void* d_out, int out_size, void* d_ws, size_t ws_size,
                              hipStream_t stream) {
    const float* x = (const float*)d_in[0];
    const float* gate_w = (const float*)d_in[1];
    const float* expert_gate = (const float*)d_in[2];
    const float* expert_up = (const float*)d_in[3];
    const float* expert_down = (const float*)d_in[4];
    const float* shared_gate = (const float*)d_in[5];
    const float* shared_up = (const float*)d_in[6];
    const float* shared_down = (const float*)d_in[7];
    float* out = (float*)d_out;

    char* w = (char*)d_ws;
    size_t off = 0;
    auto alloc = [&](size_t bytes) {
        void* p = w + off;
        off = (off + bytes + 255) & ~(size_t)255;
        return p;
    };

    // Peak ~167 MB (R2/R4 proved available).
    __bf16* xb = (__bf16*)alloc((size_t)T_TOK * H_DIM * 2);                 // 16.8 MB
    __bf16* wbuf = (__bf16*)alloc((size_t)N_EXP * I_DIM * H_DIM * 2);       // 46.1 MB (reused 6x)
    __bf16* hid = (__bf16*)alloc((size_t)CAP_SLOTS * I_DIM * 2);            // 103.8 MB
    int* topi = (int*)alloc((size_t)T_TOK * 2 * 4);
    float* topw = (float*)alloc((size_t)T_TOK * 2 * 4);
    int* tile_e = (int*)alloc(MAX_TILES * 4);
    int* tile_k = (int*)alloc(MAX_TILES * 4);
    int* token_ids = (int*)alloc((size_t)CAP_SLOTS * 4);
    float* token_w = (float*)alloc((size_t)CAP_SLOTS * 4);

    // 1) x -> bf16
    conv_kernel<<<T_TOK * H_DIM / 1024, 256, 0, stream>>>(x, xb, T_TOK * H_DIM / 4);

    // 2) router (no atomics) -> single-wave build (histogram/bases/tiles/slots)
    router_kernel<<<T_TOK / 4, 256, 0, stream>>>(x, gate_w, topi, topw);
    route_build_kernel<<<1, 64, 0, stream>>>(topi, topw, token_ids, token_w, tile_e, tile_k);

    const int nI4 = I_DIM * H_DIM / 4;            // one shared proj, f32x4 count
    const int nE4 = N_EXP * I_DIM * H_DIM / 4;    // all-expert proj

    // 3) shared expert: gate -> up(RMW) -> down(writes out directly)
    conv_kernel<<<nI4 / 256, 256, 0, stream>>>(shared_gate, wbuf, nI4);
    gemm_k<0, H_DIM, I_DIM><<<dim3(T_TOK / 128, I_DIM / 128), 256, 0, stream>>>(
        xb, wbuf, hid, nullptr, nullptr, nullptr, nullptr, nullptr, 0);
    conv_kernel<<<nI4 / 256, 256, 0, stream>>>(shared_up, wbuf, nI4);
    gemm_k<1, H_DIM, I_DIM><<<dim3(T_TOK / 128, I_DIM / 128), 256, 0, stream>>>(
        xb, wbuf, hid, nullptr, nullptr, nullptr, nullptr, nullptr, 0);
    conv_kernel<<<nI4 / 256, 256, 0, stream>>>(shared_down, wbuf, nI4);
    gemm_k<2, I_DIM, H_DIM><<<dim3(T_TOK / 128, H_DIM / 128), 256, 0, stream>>>(
        hid, wbuf, nullptr, out, nullptr, nullptr, nullptr, nullptr, 0);

    // 4) routed experts: gate -> up(RMW) -> down k0/k1 (RMW out, no races)
    conv_kernel<<<nE4 / 256, 256, 0, stream>>>(expert_gate, wbuf, nE4);
    gemm_k<0, H_DIM, I_DIM><<<dim3(MAX_TILES, I_DIM / 128), 256, 0, stream>>>(
        xb, wbuf, hid, nullptr, token_ids, token_w, tile_e, tile_k, 0);
    conv_kernel<<<nE4 / 256, 256, 0, stream>>>(expert_up, wbuf, nE4);
    gemm_k<1, H_DIM, I_DIM><<<dim3(MAX_TILES, I_DIM / 128), 256, 0, stream>>>(
        xb, wbuf, hid, nullptr, token_ids, token_w, tile_e, tile_k, 0);
    conv_kernel<<<nE4 / 256, 256, 0, stream>>>(expert_down, wbuf, nE4);
    gemm_k<3, I_DIM, H_DIM><<<dim3(MAX_TILES, H_DIM / 128), 256, 0, stream>>>(
        hid, wbuf, nullptr, out, token_ids, token_w, tile_e, tile_k, 0);
    gemm_k<3, I_DIM, H_DIM><<<dim3(MAX_TILES, H_DIM / 128), 256, 0, stream>>>(
        hid, wbuf, nullptr, out, token_ids, token_w, tile_e, tile_k, 1);
}